// Round 8
// baseline (46.222 us; speedup 1.0000x reference)
//
#include <hip/hip_runtime.h>
#include <cstdint>

typedef unsigned short u16;
typedef unsigned int u32;
typedef __bf16 bf16x8 __attribute__((ext_vector_type(8)));
typedef float f32x4 __attribute__((ext_vector_type(4)));

#define N_ROWS 4096
#define D_COLS 512

#if __has_builtin(__builtin_amdgcn_exp2f)
#define EXP2(x) __builtin_amdgcn_exp2f(x)
#else
#define EXP2(x) exp2f(x)
#endif

__device__ __forceinline__ u16 f2bf(float f) {
    u32 u = __float_as_uint(f);
    u += 0x7fffu + ((u >> 16) & 1u);
    return (u16)(u >> 16);
}

#define GLDS(g, l)                                                            \
    __builtin_amdgcn_global_load_lds(                                         \
        (const __attribute__((address_space(1))) void*)(g),                   \
        (__attribute__((address_space(3))) void*)(l), 16, 0, 0)

// ---------------- kernel 1: convert + row norms + partial column sums -------
__global__ __launch_bounds__(256) void k_prep(const float* __restrict__ X,
                                              u16* __restrict__ Xb,
                                              float* __restrict__ sq,
                                              float* __restrict__ partial) {
    __shared__ float cs[4][512];
    const int tid = threadIdx.x;
    const int w = tid >> 6, l = tid & 63;
    const int row0 = blockIdx.x * 16 + w * 4;
    float csum[8] = {0.f,0.f,0.f,0.f,0.f,0.f,0.f,0.f};
#pragma unroll
    for (int r = 0; r < 4; ++r) {
        const int row = row0 + r;
        const float4* src = (const float4*)(X + (size_t)row * D_COLS);
        float4 f0 = src[l * 2];
        float4 f1 = src[l * 2 + 1];
        float v[8] = {f0.x, f0.y, f0.z, f0.w, f1.x, f1.y, f1.z, f1.w};
        float ss = 0.f;
#pragma unroll
        for (int j = 0; j < 8; ++j) { ss += v[j] * v[j]; csum[j] += v[j]; }
        uint4 st;
        st.x = (u32)f2bf(v[0]) | ((u32)f2bf(v[1]) << 16);
        st.y = (u32)f2bf(v[2]) | ((u32)f2bf(v[3]) << 16);
        st.z = (u32)f2bf(v[4]) | ((u32)f2bf(v[5]) << 16);
        st.w = (u32)f2bf(v[6]) | ((u32)f2bf(v[7]) << 16);
        *(uint4*)(Xb + (size_t)row * D_COLS + l * 8) = st;
#pragma unroll
        for (int m = 32; m > 0; m >>= 1) ss += __shfl_xor(ss, m, 64);
        if (l == 0) sq[row] = ss;
    }
#pragma unroll
    for (int j = 0; j < 8; ++j) cs[w][l * 8 + j] = csum[j];
    __syncthreads();
    for (int d = tid; d < 512; d += 256)
        partial[blockIdx.x * 512 + d] = cs[0][d] + cs[1][d] + cs[2][d] + cs[3][d];
}

// ---------------- kernel 2: S1/S2 partials, 8 blocks ------------------------
__global__ __launch_bounds__(256) void k_sigma(const float* __restrict__ sq,
                                               const float* __restrict__ partial,
                                               float* __restrict__ parts) {
    __shared__ float csm[4][64];
    __shared__ float red[8];
    const int g = blockIdx.x;
    const int t = threadIdx.x;
    const int c = g * 64 + (t & 63);
    const int ch = t >> 6;
    float cssum = 0.f;
#pragma unroll 8
    for (int b = ch * 64; b < ch * 64 + 64; ++b) cssum += partial[b * 512 + c];
    csm[ch][t & 63] = cssum;
    float s1 = sq[g * 512 + t] + sq[g * 512 + 256 + t];
    __syncthreads();
    float s2 = 0.f;
    if (t < 64) {
        float v = csm[0][t] + csm[1][t] + csm[2][t] + csm[3][t];
        s2 = v * v;
    }
#pragma unroll
    for (int m = 32; m > 0; m >>= 1) {
        s1 += __shfl_xor(s1, m, 64);
        s2 += __shfl_xor(s2, m, 64);
    }
    if ((t & 63) == 0) { red[ch] = s1; red[4 + ch] = s2; }
    __syncthreads();
    if (t == 0) {
        parts[g] = red[0] + red[1] + red[2] + red[3];
        parts[8 + g] = red[4];
    }
}

// ---------------- kernel 3: symmetric 128x128 GEMM, upper-tri tiles only ----
// 528 blocks (ti<=tj), 4 waves (2x2), BK=64, dbuf, straight+mirror stores.
__global__ __launch_bounds__(256, 2) void k_gemm(const u16* __restrict__ Xb,
                                                 const float* __restrict__ sq,
                                                 const float* __restrict__ parts,
                                                 float* __restrict__ out) {
    __shared__ __align__(16) char pool[65536];      // staging; epilogue overlay
    __shared__ float sqA[128], sqB[128];
    __shared__ float c_sh;

    const int tid = threadIdx.x;
    const int lane = tid & 63;
    const int wid = tid >> 6;
    const int wr = wid >> 1, wc = wid & 1;           // 2x2 waves, 64x64 each

    // T1: XCD-chunked triangular tile decode. 528 = 8 XCDs x 66 (bijective).
    const int L = (blockIdx.x & 7) * 66 + (blockIdx.x >> 3);   // 0..527
    int ti = 0, rem = L;
    while (rem >= 32 - ti) { rem -= 32 - ti; ++ti; }
    const int tj = ti + rem;                         // ti <= tj
    const int i0 = ti * 128, j0 = tj * 128;
    const bool mirror = (ti != tj);

    // staging map: T2 swizzle pre-applied on global source; LDS dest linear.
    const int strow = tid >> 3;                      // 0..31
    const int sslot = (tid & 7) ^ (strow & 7);
    const char* xb = (const char*)Xb;
    const char* gA = xb + (size_t)(i0 + strow) * 1024 + sslot * 16;
    const char* gB = xb + (size_t)(j0 + strow) * 1024 + sslot * 16;

#define STAGE(buf, kt)                                                        \
    do {                                                                      \
        _Pragma("unroll")                                                     \
        for (int s = 0; s < 4; ++s) {                                         \
            GLDS(gA + s * 32768 + (kt) * 128,                                 \
                 pool + (buf) * 16384 + s * 4096 + tid * 16);                 \
            GLDS(gB + s * 32768 + (kt) * 128,                                 \
                 pool + 32768 + (buf) * 16384 + s * 4096 + tid * 16);         \
        }                                                                     \
    } while (0)

    // prologue: stage tile 0; sq + c while loads fly
    STAGE(0, 0);
    if (tid < 128) sqA[tid] = sq[i0 + tid];
    else           sqB[tid - 128] = sq[j0 + tid - 128];
    if (tid == 0) {
        float S1 = 0.f, S2 = 0.f;
#pragma unroll
        for (int i = 0; i < 8; ++i) { S1 += parts[i]; S2 += parts[8 + i]; }
        const float mean_d2 = 2.f * S1 / (float)N_ROWS
                            - 2.f * S2 / ((float)N_ROWS * (float)N_ROWS);
        c_sh = -1.4426950408889634f / (2.f * mean_d2);   // ALPHA=1
    }

    f32x4 acc[4][4];
#pragma unroll
    for (int m = 0; m < 4; ++m)
#pragma unroll
        for (int n = 0; n < 4; ++n) acc[m][n] = (f32x4){0.f, 0.f, 0.f, 0.f};

    const int frow = lane & 15;
    const int klane = lane >> 4;
    const int q = lane >> 4;
    const int s0 = (klane ^ (frow & 7)) << 4;        // read-side swizzled slot

    for (int kt = 0; kt < 8; ++kt) {
        const int buf = kt & 1;
        __syncthreads();                 // implicit vmcnt(0)+lgkm(0)+barrier
        if (kt < 7) STAGE(buf ^ 1, kt + 1);
        const char* Ab = pool + buf * 16384;
        const char* Bb = pool + 32768 + buf * 16384;
#pragma unroll
        for (int ks = 0; ks < 2; ++ks) {
            const int kb = s0 ^ (ks << 6);
            bf16x8 a[4], b[4];
#pragma unroll
            for (int i = 0; i < 4; ++i)
                a[i] = *(const bf16x8*)(Ab + (wr * 64 + i * 16 + frow) * 128 + kb);
#pragma unroll
            for (int n = 0; n < 4; ++n)
                b[n] = *(const bf16x8*)(Bb + (wc * 64 + n * 16 + frow) * 128 + kb);
            __builtin_amdgcn_s_setprio(1);
#pragma unroll
            for (int i = 0; i < 4; ++i)
#pragma unroll
                for (int n = 0; n < 4; ++n)
                    acc[i][n] = __builtin_amdgcn_mfma_f32_16x16x32_bf16(
                        a[i], b[n], acc[i][n], 0, 0, 0);
            __builtin_amdgcn_s_setprio(0);
        }
    }
#undef STAGE

    // ---- epilogue: exp once; straight store via LDS tile; mirror direct ----
    __syncthreads();                 // K-loop LDS dead, safe to overlay
    float (*eps)[132] = (float (*)[132])pool;        // 16.9 KB overlay
    const float cval = c_sh;
    const int lrow = tid >> 3;       // 0..31
    const int seg = tid & 7;         // 0..7
#pragma unroll
    for (int m = 0; m < 4; ++m) {
#pragma unroll
        for (int n = 0; n < 4; ++n) {
            const int col = wc * 64 + n * 16 + frow;
            const float sb = sqB[col];
            float4 mv;
#pragma unroll
            for (int r = 0; r < 4; ++r) {
                const int row = wr * 64 + m * 16 + q * 4 + r;
                const float d2 = sqA[row] + sb - 2.0f * acc[m][n][r];
                const float e = EXP2(cval * d2);
                eps[wr * 16 + q * 4 + r][col] = e;
                ((float*)&mv)[r] = e;
            }
            // mirror tile (tj,ti): lane's 4 regs are 4 consecutive rows ->
            // one float4 at out-row j0+col, cols i0+wr*64+m*16+q*4..+3
            if (mirror)
                *(float4*)(out + (size_t)(j0 + col) * N_ROWS +
                           i0 + wr * 64 + m * 16 + q * 4) = mv;
        }
        __syncthreads();             // eps tile complete
        const int grow = i0 + (lrow >> 4) * 64 + m * 16 + (lrow & 15);
        float4* orow = (float4*)(out + (size_t)grow * N_ROWS + j0);
        const float* er = eps[lrow];
#pragma unroll
        for (int s = 0; s < 4; ++s) {
            const int f4 = seg + s * 8;
            orow[f4] = *(const float4*)(er + f4 * 4);
        }
        __syncthreads();             // safe to rewrite eps next m
    }
}

extern "C" void kernel_launch(void* const* d_in, const int* in_sizes, int n_in,
                              void* d_out, int out_size, void* d_ws, size_t ws_size,
                              hipStream_t stream) {
    const float* X = (const float*)d_in[0];
    float* out = (float*)d_out;
    char* ws = (char*)d_ws;

    u16*   Xb   = (u16*)ws;                                   // 4 MB
    float* part = (float*)(ws + (4u << 20));                  // 512 KB
    float* sq   = (float*)(ws + (4u << 20) + (512u << 10));   // 16 KB
    float* prt  = (float*)(ws + (4u << 20) + (512u << 10) + (16u << 10));

    hipLaunchKernelGGL(k_prep, dim3(256), dim3(256), 0, stream, X, Xb, sq, part);
    hipLaunchKernelGGL(k_sigma, dim3(8), dim3(256), 0, stream, sq, part, prt);
    hipLaunchKernelGGL(k_gemm, dim3(528), dim3(256), 0, stream, Xb, sq, prt, out);
}